// Round 1
// baseline (2746.128 us; speedup 1.0000x reference)
//
#include <hip/hip_runtime.h>
#include <stdint.h>

// Borůvka maximum-spanning-forest == Kruskal acceptance set under a strict
// total order (score desc, index asc). V hardcoded from reference NUM_NODES.
#define V_NODES 100000
#define R_ROUNDS 18   // components at least halve per active round; 2^17 > 1e5

__device__ __forceinline__ int find_root(const int* __restrict__ parent, int v) {
    int p = parent[v];
    int pp = parent[p];
    while (p != pp) { p = pp; pp = parent[p]; }
    return p;
}

// key = (~monotone_f32(score) << 32) | edge_idx  — min-key == best edge
// (largest score, ties -> smallest index, matching stable argsort(-scores)).
__global__ void k_keys(const float* __restrict__ s, const float* __restrict__ u,
                       unsigned long long* __restrict__ key,
                       float* __restrict__ out, int E) {
    int e = blockIdx.x * blockDim.x + threadIdx.x;
    if (e >= E) return;
    float sv = s[e], uv = u[e];
    float sp = 1.0f / (1.0f + expf(-sv));                 // sigmoid, f32 chain
    float g  = -logf(-logf(uv + 1e-9f) + 1e-9f);          // gumbel, f32 chain
    float score = sp + g;
    unsigned int b = __float_as_uint(score);
    unsigned int m = (b & 0x80000000u) ? ~b : (b | 0x80000000u); // ascending map
    unsigned int hi = ~m;                                        // descending
    key[e] = ((unsigned long long)hi << 32) | (unsigned int)e;
    out[e] = 0.0f;   // harness poisons d_out before timed replays
}

__global__ void k_init(int* __restrict__ parent, unsigned long long* __restrict__ best,
                       int* __restrict__ hook, int* __restrict__ changed, int V) {
    int v = blockIdx.x * blockDim.x + threadIdx.x;
    if (v >= V) return;
    parent[v] = v;
    best[v] = ~0ULL;
    hook[v] = -1;
    if (v < R_ROUNDS) changed[v] = 0;
}

// Per-edge: if endpoints in different components, bid for both components' best.
__global__ void k_scan(const int* __restrict__ src, const int* __restrict__ dst,
                       const unsigned long long* __restrict__ key,
                       const int* __restrict__ parent,
                       unsigned long long* __restrict__ best,
                       int* __restrict__ changed, int r, int E) {
    if (r > 0 && changed[r - 1] == 0) return;
    int e = blockIdx.x * blockDim.x + threadIdx.x;
    if (e >= E) return;
    int ru = find_root(parent, src[e]);
    int rv = find_root(parent, dst[e]);
    if (ru == rv) return;
    unsigned long long k = key[e];
    atomicMin(&best[ru], k);
    atomicMin(&best[rv], k);
    changed[r] = 1;   // benign race, same value
}

// Per-root: mark chosen edge in output (cut property => in MSF), propose hook.
// Mutual pair (both chose same edge) broken by root id to avoid 2-cycles.
__global__ void k_choose(const int* __restrict__ src, const int* __restrict__ dst,
                         const int* __restrict__ parent,
                         const unsigned long long* __restrict__ best,
                         int* __restrict__ hook, float* __restrict__ out,
                         const int* __restrict__ changed, int r, int V) {
    if (r > 0 && changed[r - 1] == 0) return;
    int v = blockIdx.x * blockDim.x + threadIdx.x;
    if (v >= V) return;
    unsigned long long k = best[v];
    if (k == ~0ULL) return;
    int e = (int)(unsigned int)(k & 0xffffffffu);
    int ru = find_root(parent, src[e]);
    int rv = find_root(parent, dst[e]);
    int other = (ru == v) ? rv : ru;
    out[e] = 1.0f;
    bool mutual = (best[other] == k);
    if (!mutual || v > other) hook[v] = other;
}

// Apply hooks; reset best/hook for next round.
__global__ void k_hookreset(int* __restrict__ parent, unsigned long long* __restrict__ best,
                            int* __restrict__ hook,
                            const int* __restrict__ changed, int r, int V) {
    if (r > 0 && changed[r - 1] == 0) return;
    int v = blockIdx.x * blockDim.x + threadIdx.x;
    if (v >= V) return;
    int h = hook[v];
    if (h >= 0) { parent[v] = h; hook[v] = -1; }
    best[v] = ~0ULL;
}

__global__ void k_jump(int* __restrict__ parent,
                       const int* __restrict__ changed, int r, int V) {
    if (r > 0 && changed[r - 1] == 0) return;
    int v = blockIdx.x * blockDim.x + threadIdx.x;
    if (v >= V) return;
    int p = parent[v];
    int gp = parent[p];
    if (p != gp) parent[v] = gp;   // benign race: values only move toward root
}

extern "C" void kernel_launch(void* const* d_in, const int* in_sizes, int n_in,
                              void* d_out, int out_size, void* d_ws, size_t ws_size,
                              hipStream_t stream) {
    const float* s  = (const float*)d_in[0];
    const float* u  = (const float*)d_in[1];
    const int*   ei = (const int*)d_in[2];
    const int E = in_sizes[0];
    const int* src = ei;
    const int* dst = ei + E;
    float* out = (float*)d_out;

    char* ws = (char*)d_ws;
    unsigned long long* key  = (unsigned long long*)ws;                       // E*8
    unsigned long long* best = (unsigned long long*)(ws + (size_t)E * 8);     // V*8
    int* parent  = (int*)(ws + (size_t)E * 8 + (size_t)V_NODES * 8);          // V*4
    int* hook    = parent + V_NODES;                                          // V*4
    int* changed = hook + V_NODES;                                            // R*4

    const int tb = 256;
    const int gE = (E + tb - 1) / tb;
    const int gV = (V_NODES + tb - 1) / tb;

    k_keys<<<gE, tb, 0, stream>>>(s, u, key, out, E);
    k_init<<<gV, tb, 0, stream>>>(parent, best, hook, changed, V_NODES);

    for (int r = 0; r < R_ROUNDS; ++r) {
        k_scan<<<gE, tb, 0, stream>>>(src, dst, key, parent, best, changed, r, E);
        k_choose<<<gV, tb, 0, stream>>>(src, dst, parent, best, hook, out, changed, r, V_NODES);
        k_hookreset<<<gV, tb, 0, stream>>>(parent, best, hook, changed, r, V_NODES);
        k_jump<<<gV, tb, 0, stream>>>(parent, changed, r, V_NODES);
        k_jump<<<gV, tb, 0, stream>>>(parent, changed, r, V_NODES);
    }
}